// Round 11
// baseline (1879.886 us; speedup 1.0000x reference)
//
#include <hip/hip_runtime.h>
#include <hip/hip_bf16.h>
#include <hip/hip_cooperative_groups.h>

namespace cg = cooperative_groups;

typedef __attribute__((ext_vector_type(8))) short short8;
typedef __attribute__((ext_vector_type(8))) unsigned short ushort8;
typedef __attribute__((ext_vector_type(4))) float f32x4;

static constexpr int NN = 50000;   // nodes
static constexpr int NE = 800000;  // edges
static constexpr int SCAN_B = 196; // ceil(NN/256)
static constexpr int MEGA_B = 1024;

#define MFMA16x16x32 __builtin_amdgcn_mfma_f32_16x16x32_bf16

__device__ __forceinline__ float b2f(unsigned short u){
  unsigned v = ((unsigned)u) << 16;
  return __builtin_bit_cast(float, v);
}
__device__ __forceinline__ unsigned short f2b(float f){
  unsigned x = __builtin_bit_cast(unsigned, f);
  unsigned r = (x + 0x7fffu + ((x >> 16) & 1u)) >> 16;  // RNE
  return (unsigned short)r;
}

// ---------------- static device scratch
__device__ __align__(256) int   g_isf32;
__device__ __align__(256) unsigned short g_W1t  [112 * 512];
__device__ __align__(256) unsigned short g_W2t  [112 * 128];
__device__ __align__(256) unsigned short g_WselfT[112 * 128];
__device__ __align__(256) unsigned short g_WrelT [112 * 128];
__device__ __align__(256) unsigned short g_c1Wt [112 * 128];
__device__ __align__(256) unsigned short g_c2Wt [64 * 128];
__device__ __align__(256) unsigned short g_bufA[(size_t)NN * 128];
__device__ __align__(256) unsigned short g_bufB[(size_t)NN * 128];
__device__ __align__(256) unsigned short g_bufC[(size_t)NN * 128];
__device__ __align__(256) int   g_deg[NN];
__device__ __align__(256) int   g_rowptr[NN + 1];
__device__ __align__(256) int   g_cursor[NN];
__device__ __align__(256) int   g_colidx[NE];
__device__ __align__(256) float g_dinv[NN];
__device__ __align__(256) int   g_partial[256];

__device__ __forceinline__ float ld_in(const void* p, int idx, int isf32){
  if (isf32) return ((const float*)p)[idx];
  return b2f(((const unsigned short*)p)[idx]);
}

// ================= shared phase bodies =================

// GEMM2 + LN + ReLU: bufA[row0..row0+16) @ W2t -> bufB
__device__ __forceinline__ void body_gemm2_ln(int row0, int m, int q, int isf32,
    const void* bias, const void* gamma, const void* beta){
  f32x4 acc[7] = {};
  const unsigned short* arow = g_bufA + (size_t)(row0 + m) * 128;
#pragma unroll
  for (int c = 0; c < 4; c++){
    const int k0 = c * 32 + q * 8;
    short8 a = *reinterpret_cast<const short8*>(arow + k0);
#pragma unroll
    for (int t = 0; t < 7; t++){
      short8 b = *reinterpret_cast<const short8*>(g_W2t + (size_t)(t * 16 + m) * 128 + k0);
      acc[t] = MFMA16x16x32(a, b, acc[t], 0, 0, 0);
    }
  }
  float bf_[7], gf_[7], ef_[7];
#pragma unroll
  for (int t = 0; t < 7; t++){
    int col = t * 16 + m;
    bool ok = col < 100;
    bf_[t] = ok ? ld_in(bias, col, isf32)  : 0.f;
    gf_[t] = ok ? ld_in(gamma, col, isf32) : 0.f;
    ef_[t] = ok ? ld_in(beta, col, isf32)  : 0.f;
  }
#pragma unroll
  for (int r = 0; r < 4; r++){
    float vals[7], s1 = 0.f, s2 = 0.f;
#pragma unroll
    for (int t = 0; t < 7; t++){
      int col = t * 16 + m;
      float v = (col < 100) ? (acc[t][r] + bf_[t]) : 0.f;
      vals[t] = v; s1 += v; s2 += v * v;
    }
#pragma unroll
    for (int msk = 1; msk < 16; msk <<= 1){
      s1 += __shfl_xor(s1, msk, 64);
      s2 += __shfl_xor(s2, msk, 64);
    }
    float mu = s1 * 0.01f;
    float var = fmaxf(s2 * 0.01f - mu * mu, 0.f);
    float rstd = rsqrtf(var + 1e-5f);
    unsigned short* orow = g_bufB + (size_t)(row0 + q * 4 + r) * 128;
#pragma unroll
    for (int t = 0; t < 7; t++){
      int col = t * 16 + m;
      float y = fmaxf((vals[t] - mu) * rstd * gf_[t] + ef_[t], 0.f);
      orow[col] = f2b((col < 100) ? y : 0.f);
    }
    orow[112 + m] = 0;
  }
}

// RGCN dual GEMM + bias + ReLU: bufB@Wself + bufA@Wrel -> bufC
__device__ __forceinline__ void body_rgcn(int row0, int m, int q, int isf32,
                                          const void* bias){
  f32x4 acc[7] = {};
  const unsigned short* a1row = g_bufB + (size_t)(row0 + m) * 128;
#pragma unroll
  for (int c = 0; c < 4; c++){
    const int k0 = c * 32 + q * 8;
    short8 a = *reinterpret_cast<const short8*>(a1row + k0);
#pragma unroll
    for (int t = 0; t < 7; t++){
      short8 b = *reinterpret_cast<const short8*>(g_WselfT + (size_t)(t * 16 + m) * 128 + k0);
      acc[t] = MFMA16x16x32(a, b, acc[t], 0, 0, 0);
    }
  }
  const unsigned short* a2row = g_bufA + (size_t)(row0 + m) * 128;
#pragma unroll
  for (int c = 0; c < 4; c++){
    const int k0 = c * 32 + q * 8;
    short8 a = *reinterpret_cast<const short8*>(a2row + k0);
#pragma unroll
    for (int t = 0; t < 7; t++){
      short8 b = *reinterpret_cast<const short8*>(g_WrelT + (size_t)(t * 16 + m) * 128 + k0);
      acc[t] = MFMA16x16x32(a, b, acc[t], 0, 0, 0);
    }
  }
  float bf_[7];
#pragma unroll
  for (int t = 0; t < 7; t++){
    int col = t * 16 + m;
    bf_[t] = (col < 100) ? ld_in(bias, col, isf32) : 0.f;
  }
#pragma unroll
  for (int r = 0; r < 4; r++){
    unsigned short* orow = g_bufC + (size_t)(row0 + q * 4 + r) * 128;
#pragma unroll
    for (int t = 0; t < 7; t++){
      int col = t * 16 + m;
      float y = fmaxf(acc[t][r] + bf_[t], 0.f);
      orow[col] = f2b((col < 100) ? y : 0.f);
    }
    orow[112 + m] = 0;
  }
}

// conv1 GEMM + bias + ReLU: bufA @ c1Wt -> bufB
__device__ __forceinline__ void body_conv1(int row0, int m, int q, int isf32,
                                           const void* bias){
  f32x4 acc[7] = {};
  const unsigned short* a1row = g_bufA + (size_t)(row0 + m) * 128;
#pragma unroll
  for (int c = 0; c < 4; c++){
    const int k0 = c * 32 + q * 8;
    short8 a = *reinterpret_cast<const short8*>(a1row + k0);
#pragma unroll
    for (int t = 0; t < 7; t++){
      short8 b = *reinterpret_cast<const short8*>(g_c1Wt + (size_t)(t * 16 + m) * 128 + k0);
      acc[t] = MFMA16x16x32(a, b, acc[t], 0, 0, 0);
    }
  }
  float bf_[7];
#pragma unroll
  for (int t = 0; t < 7; t++){
    int col = t * 16 + m;
    bf_[t] = (col < 100) ? ld_in(bias, col, isf32) : 0.f;
  }
#pragma unroll
  for (int r = 0; r < 4; r++){
    unsigned short* orow = g_bufB + (size_t)(row0 + q * 4 + r) * 128;
#pragma unroll
    for (int t = 0; t < 7; t++){
      int col = t * 16 + m;
      float y = fmaxf(acc[t][r] + bf_[t], 0.f);
      orow[col] = f2b((col < 100) ? y : 0.f);
    }
    orow[112 + m] = 0;
  }
}

// conv2 GEMM only: bufB @ c2Wt -> bufC [N,64] (bias after aggregation)
__device__ __forceinline__ void body_c2(int row0, int m, int q){
  f32x4 acc[4] = {};
  const unsigned short* arow = g_bufB + (size_t)(row0 + m) * 128;
#pragma unroll
  for (int c = 0; c < 4; c++){
    const int k0 = c * 32 + q * 8;
    short8 a = *reinterpret_cast<const short8*>(arow + k0);
#pragma unroll
    for (int t = 0; t < 4; t++){
      short8 b = *reinterpret_cast<const short8*>(g_c2Wt + (size_t)(t * 16 + m) * 128 + k0);
      acc[t] = MFMA16x16x32(a, b, acc[t], 0, 0, 0);
    }
  }
#pragma unroll
  for (int r = 0; r < 4; r++){
    unsigned short* orow = g_bufC + (size_t)(row0 + q * 4 + r) * 64;
#pragma unroll
    for (int t = 0; t < 4; t++) orow[t * 16 + m] = f2b(acc[t][r]);
  }
}

// gather-aggregate (128-col rows). MODE 0: plain sum bufB->bufA. MODE 1: norm bufC->bufA. 
template<int MODE>
__device__ __forceinline__ void body_agg(int node, int c8){
  const unsigned short* x = (MODE == 1) ? g_bufC : g_bufB;
  float wt = (MODE != 0) ? g_dinv[node] : 1.f;
  float a[4][8];
#pragma unroll
  for (int j = 0; j < 4; j++)
#pragma unroll
    for (int k = 0; k < 8; k++) a[j][k] = 0.f;
  int p0 = g_rowptr[node], p1 = g_rowptr[node + 1];
  for (int p = p0; p < p1; p += 4){
    int sj[4]; float wj[4];
#pragma unroll
    for (int j = 0; j < 4; j++){
      bool ok = (p + j) < p1;
      sj[j] = ok ? g_colidx[p + j] : node;
      wj[j] = ok ? ((MODE != 0) ? g_dinv[sj[j]] * wt : 1.f) : 0.f;
    }
    ushort8 r[4];
#pragma unroll
    for (int j = 0; j < 4; j++)
      r[j] = *reinterpret_cast<const ushort8*>(&x[(size_t)sj[j] * 128 + c8]);
#pragma unroll
    for (int j = 0; j < 4; j++)
#pragma unroll
      for (int k = 0; k < 8; k++) a[j][k] += wj[j] * b2f((unsigned short)r[j][k]);
  }
  if (MODE != 0){
    float ws = wt * wt;
    ushort8 sv = *reinterpret_cast<const ushort8*>(&x[(size_t)node * 128 + c8]);
#pragma unroll
    for (int k = 0; k < 8; k++) a[0][k] += ws * b2f((unsigned short)sv[k]);
  }
  ushort8 o;
#pragma unroll
  for (int k = 0; k < 8; k++)
    o[k] = f2b(a[0][k] + a[1][k] + a[2][k] + a[3][k]);
  *reinterpret_cast<ushort8*>(&g_bufA[(size_t)node * 128 + c8]) = o;
}

// conv2 aggregate (64-col) + bias + log_softmax -> out
__device__ __forceinline__ void body_agglsm(int node, int c8, int isf32,
                                            const void* bias, void* outv){
  float wt = g_dinv[node];
  float a[4][8];
#pragma unroll
  for (int j = 0; j < 4; j++)
#pragma unroll
    for (int k = 0; k < 8; k++) a[j][k] = 0.f;
  int p0 = g_rowptr[node], p1 = g_rowptr[node + 1];
  for (int p = p0; p < p1; p += 4){
    int sj[4]; float wj[4];
#pragma unroll
    for (int j = 0; j < 4; j++){
      bool ok = (p + j) < p1;
      sj[j] = ok ? g_colidx[p + j] : node;
      wj[j] = ok ? g_dinv[sj[j]] * wt : 0.f;
    }
    ushort8 r[4];
#pragma unroll
    for (int j = 0; j < 4; j++)
      r[j] = *reinterpret_cast<const ushort8*>(&g_bufC[(size_t)sj[j] * 64 + c8]);
#pragma unroll
    for (int j = 0; j < 4; j++)
#pragma unroll
      for (int k = 0; k < 8; k++) a[j][k] += wj[j] * b2f((unsigned short)r[j][k]);
  }
  float ws = wt * wt;
  ushort8 sv = *reinterpret_cast<const ushort8*>(&g_bufC[(size_t)node * 64 + c8]);
#pragma unroll
  for (int k = 0; k < 8; k++) a[0][k] += ws * b2f((unsigned short)sv[k]);

  float v[8], mx = -1e30f;
#pragma unroll
  for (int k = 0; k < 8; k++){
    v[k] = a[0][k] + a[1][k] + a[2][k] + a[3][k] + ld_in(bias, c8 + k, isf32);
    mx = fmaxf(mx, v[k]);
  }
#pragma unroll
  for (int msk = 1; msk < 8; msk <<= 1) mx = fmaxf(mx, __shfl_xor(mx, msk, 64));
  float se = 0.f;
#pragma unroll
  for (int k = 0; k < 8; k++) se += expf(v[k] - mx);
#pragma unroll
  for (int msk = 1; msk < 8; msk <<= 1) se += __shfl_xor(se, msk, 64);
  float lse = logf(se);
  size_t ro = (size_t)node * 64 + c8;
  if (isf32){
    float* o = (float*)outv + ro;
#pragma unroll
    for (int k = 0; k < 8; k++) o[k] = v[k] - mx - lse;
  } else {
    unsigned short* o = (unsigned short*)outv + ro;
#pragma unroll
    for (int k = 0; k < 8; k++) o[k] = f2b(v[k] - mx - lse);
  }
}

// GEMM1 compute (K-split): wave w handles K in [128w,128w+128) of 16 rows.
__device__ __forceinline__ void body_gemm1_compute(const void* Aext, int row0,
    int m, int q, int kbase, int isf32, f32x4* acc){
  if (isf32){
    const float* base = (const float*)Aext + (size_t)(row0 + m) * 500;
    f32x4 L[8];
#pragma unroll
    for (int c = 0; c < 4; c++){
      int col = kbase + c * 32 + q * 8;
      L[2 * c]     = *reinterpret_cast<const f32x4*>(base + min(col, 496));
      L[2 * c + 1] = *reinterpret_cast<const f32x4*>(base + min(col + 4, 496));
    }
#pragma unroll
    for (int c = 0; c < 4; c++){
      f32x4 lo = L[2 * c], hi = L[2 * c + 1];
      short8 a = {(short)f2b(lo[0]), (short)f2b(lo[1]), (short)f2b(lo[2]), (short)f2b(lo[3]),
                  (short)f2b(hi[0]), (short)f2b(hi[1]), (short)f2b(hi[2]), (short)f2b(hi[3])};
      const int k0 = kbase + c * 32 + q * 8;
#pragma unroll
      for (int t = 0; t < 7; t++){
        short8 b = *reinterpret_cast<const short8*>(g_W1t + (size_t)(t * 16 + m) * 512 + k0);
        acc[t] = MFMA16x16x32(a, b, acc[t], 0, 0, 0);
      }
    }
  } else {
    const unsigned short* base = (const unsigned short*)Aext + (size_t)(row0 + m) * 500;
    ushort4 U[8];
#pragma unroll
    for (int c = 0; c < 4; c++){
      int col = kbase + c * 32 + q * 8;
      U[2 * c]     = *reinterpret_cast<const ushort4*>(base + min(col, 496));
      U[2 * c + 1] = *reinterpret_cast<const ushort4*>(base + min(col + 4, 496));
    }
#pragma unroll
    for (int c = 0; c < 4; c++){
      ushort4 lo = U[2 * c], hi = U[2 * c + 1];
      short8 a = {(short)lo.x, (short)lo.y, (short)lo.z, (short)lo.w,
                  (short)hi.x, (short)hi.y, (short)hi.z, (short)hi.w};
      const int k0 = kbase + c * 32 + q * 8;
#pragma unroll
      for (int t = 0; t < 7; t++){
        short8 b = *reinterpret_cast<const short8*>(g_W1t + (size_t)(t * 16 + m) * 512 + k0);
        acc[t] = MFMA16x16x32(a, b, acc[t], 0, 0, 0);
      }
    }
  }
}

// GEMM1 epilogue (wave 0 only): reduce 4 wave-partials from red, LN, store bufA
__device__ __forceinline__ void body_gemm1_epi(const float* red, int row0,
    int lane, int m, int q, int isf32,
    const void* bias, const void* gamma, const void* beta){
  float bf_[7], gf_[7], ef_[7];
#pragma unroll
  for (int t = 0; t < 7; t++){
    int col = t * 16 + m;
    bool ok = col < 100;
    bf_[t] = ok ? ld_in(bias, col, isf32)  : 0.f;
    gf_[t] = ok ? ld_in(gamma, col, isf32) : 0.f;
    ef_[t] = ok ? ld_in(beta, col, isf32)  : 0.f;
  }
#pragma unroll
  for (int r = 0; r < 4; r++){
    float vals[7], s1 = 0.f, s2 = 0.f;
#pragma unroll
    for (int t = 0; t < 7; t++){
      const float* rv = &red[(t * 4 + r) * 256];
      float v = rv[lane] + rv[64 + lane] + rv[128 + lane] + rv[192 + lane];
      int col = t * 16 + m;
      v = (col < 100) ? (v + bf_[t]) : 0.f;
      vals[t] = v; s1 += v; s2 += v * v;
    }
#pragma unroll
    for (int msk = 1; msk < 16; msk <<= 1){
      s1 += __shfl_xor(s1, msk, 64);
      s2 += __shfl_xor(s2, msk, 64);
    }
    float mu = s1 * 0.01f;
    float var = fmaxf(s2 * 0.01f - mu * mu, 0.f);
    float rstd = rsqrtf(var + 1e-5f);
    unsigned short* orow = g_bufA + (size_t)(row0 + q * 4 + r) * 128;
#pragma unroll
    for (int t = 0; t < 7; t++){
      int col = t * 16 + m;
      float y = fmaxf((vals[t] - mu) * rstd * gf_[t] + ef_[t], 0.f);
      orow[col] = f2b((col < 100) ? y : 0.f);
    }
    orow[112 + m] = 0;
  }
}

// ================= small prep kernels =================

// block 0: dtype sniff; blocks 1..: zero deg/cursor
__global__ void k_detect_zero(const unsigned short* __restrict__ x){
  if (blockIdx.x == 0){
    __shared__ int sh[256];
    int tid = threadIdx.x;
    int cnt = 0;
    for (int j = 0; j < 16; j++){
      unsigned short h = x[(size_t)(tid * 16 + j) * 2];
      int e = (h >> 7) & 0xFF;
      if (e >= 90 && e <= 160) cnt++;
    }
    sh[tid] = cnt;
    __syncthreads();
    for (int off = 128; off > 0; off >>= 1){
      if (tid < off) sh[tid] += sh[tid + off];
      __syncthreads();
    }
    if (tid == 0) g_isf32 = (sh[0] < 2458) ? 1 : 0;
  } else {
    int i = (blockIdx.x - 1) * 256 + threadIdx.x;
    if (i < NN){ g_deg[i] = 0; g_cursor[i] = 0; }
  }
}

__device__ __forceinline__ void xp_one(const void* W, unsigned short* Wt, int idx,
                                       int K, int Nc, int Kpad, int isf32){
  int n = idx / Kpad;
  int k = idx - n * Kpad;
  float v = 0.f;
  if (n < Nc && k < K) v = ld_in(W, k * Nc + n, isf32);
  Wt[idx] = f2b(v);
}
__global__ void k_transpose_all(const void* W1, const void* W2, const void* Wself,
                                const void* Wrel, const void* c1W, const void* c2W){
  int idx = blockIdx.x * 256 + threadIdx.x;
  const int isf32 = g_isf32;
  if (idx < 57344){ xp_one(W1, g_W1t, idx, 500, 100, 512, isf32); return; }
  idx -= 57344;
  if (idx < 14336){ xp_one(W2,    g_W2t,    idx, 100, 100, 128, isf32); return; }
  idx -= 14336;
  if (idx < 14336){ xp_one(Wself, g_WselfT, idx, 100, 100, 128, isf32); return; }
  idx -= 14336;
  if (idx < 14336){ xp_one(Wrel,  g_WrelT,  idx, 100, 100, 128, isf32); return; }
  idx -= 14336;
  if (idx < 14336){ xp_one(c1W,   g_c1Wt,   idx, 100, 100, 128, isf32); return; }
  idx -= 14336;
  if (idx < 8192){  xp_one(c2W,   g_c2Wt,   idx, 100, 64,  128, isf32); }
}

// ================= MEGA cooperative kernel =================
struct MegaArgs {
  const void* data_x; const int* src; const int* tgt;
  const void *b1, *gm1, *be1, *b2, *gm2, *be2, *rb, *c1b, *c2b;
  void* out;
};

__global__ __launch_bounds__(256, 4) void k_mega(MegaArgs A){
  cg::grid_group grid = cg::this_grid();
  __shared__ __align__(16) char smem[28672];
  const int bid = blockIdx.x, tid = threadIdx.x;
  const int w = tid >> 6, lane = tid & 63;
  const int m = lane & 15, q = lane >> 4;
  const int NB = gridDim.x;
  const int nthread = NB * 256, nwave = NB * 4;
  const int gw = bid * 4 + w;
  const int isf32 = g_isf32;

  // ---- CSR: degree histogram
  for (int e = bid * 256 + tid; e < NE; e += nthread) atomicAdd(&g_deg[A.tgt[e]], 1);
  grid.sync();
  // ---- scan1 (+dinv)
  if (bid < SCAN_B){
    int* sh = (int*)smem;
    int i = bid * 256 + tid;
    int val = (i < NN) ? g_deg[i] : 0;
    sh[tid] = val; __syncthreads();
#pragma unroll
    for (int off = 1; off < 256; off <<= 1){
      int v = (tid >= off) ? sh[tid - off] : 0;
      __syncthreads(); sh[tid] += v; __syncthreads();
    }
    if (i < NN){ g_rowptr[i] = sh[tid] - val; g_dinv[i] = rsqrtf((float)(val + 1)); }
    if (tid == 255) g_partial[bid] = sh[255];
  }
  grid.sync();
  // ---- scan2
  if (bid == 0){
    int* sh = (int*)smem;
    int val = (tid < SCAN_B) ? g_partial[tid] : 0;
    sh[tid] = val; __syncthreads();
#pragma unroll
    for (int off = 1; off < 256; off <<= 1){
      int v = (tid >= off) ? sh[tid - off] : 0;
      __syncthreads(); sh[tid] += v; __syncthreads();
    }
    if (tid < SCAN_B) g_partial[tid] = sh[tid] - val;
    if (tid == 255) g_rowptr[NN] = sh[255];
  }
  grid.sync();
  // ---- scan3
  if (bid < SCAN_B){
    int i = bid * 256 + tid;
    if (i < NN) g_rowptr[i] += g_partial[bid];
  }
  grid.sync();
  // ---- CSR fill, then gemm1 (independent of fill; no sync between)
  for (int e = bid * 256 + tid; e < NE; e += nthread){
    int t = A.tgt[e];
    int pos = g_rowptr[t] + atomicAdd(&g_cursor[t], 1);
    g_colidx[pos] = A.src[e];
  }
  // ---- GEMM1 + LN (K-split across 4 waves; cross-wave reduce in LDS)
  {
    float* red = (float*)smem;
    const int kbase = w * 128;
    for (int grp = bid; grp < 3125; grp += NB){
      const int row0 = grp * 16;
      f32x4 acc[7] = {};
      body_gemm1_compute(A.data_x, row0, m, q, kbase, isf32, acc);
      __syncthreads();   // guards prev iteration's epilogue reads of red
#pragma unroll
      for (int t = 0; t < 7; t++)
#pragma unroll
        for (int r = 0; r < 4; r++)
          red[(t * 4 + r) * 256 + tid] = acc[t][r];
      __syncthreads();
      if (w == 0) body_gemm1_epi(red, row0, lane, m, q, isf32, A.b1, A.gm1, A.be1);
    }
  }
  grid.sync();
  // ---- GEMM2 + LN
  for (int grp = gw; grp < 3125; grp += nwave) body_gemm2_ln(grp * 16, m, q, isf32, A.b2, A.gm2, A.be2);
  grid.sync();
  // ---- RGCN aggregate (sum) bufB -> bufA
  for (int node = bid * 16 + (tid >> 4); node < NN; node += NB * 16)
    body_agg<0>(node, (tid & 15) * 8);
  grid.sync();
  // ---- RGCN dual GEMM -> bufC
  for (int grp = gw; grp < 3125; grp += nwave) body_rgcn(grp * 16, m, q, isf32, A.rb);
  grid.sync();
  // ---- conv1 aggregate (norm) bufC -> bufA
  for (int node = bid * 16 + (tid >> 4); node < NN; node += NB * 16)
    body_agg<1>(node, (tid & 15) * 8);
  grid.sync();
  // ---- conv1 GEMM -> bufB
  for (int grp = gw; grp < 3125; grp += nwave) body_conv1(grp * 16, m, q, isf32, A.c1b);
  grid.sync();
  // ---- conv2 GEMM -> bufC [N,64]
  for (int grp = gw; grp < 3125; grp += nwave) body_c2(grp * 16, m, q);
  grid.sync();
  // ---- conv2 aggregate + bias + log_softmax -> out
  for (int node = bid * 32 + (tid >> 3); node < NN; node += NB * 32)
    body_agglsm(node, (tid & 7) * 8, isf32, A.c2b, A.out);
}

// ================= standalone fallback kernels (R10 path) =================
__global__ void k_deg(const int* __restrict__ tgt){
  int e = blockIdx.x * 256 + threadIdx.x;
  if (e < NE) atomicAdd(&g_deg[tgt[e]], 1);
}
__global__ __launch_bounds__(256) void k_scan1(){
  __shared__ int sh[256];
  int t = threadIdx.x;
  int i = blockIdx.x * 256 + t;
  int val = (i < NN) ? g_deg[i] : 0;
  sh[t] = val; __syncthreads();
#pragma unroll
  for (int off = 1; off < 256; off <<= 1){
    int v = (t >= off) ? sh[t - off] : 0;
    __syncthreads(); sh[t] += v; __syncthreads();
  }
  if (i < NN){ g_rowptr[i] = sh[t] - val; g_dinv[i] = rsqrtf((float)(val + 1)); }
  if (t == 255) g_partial[blockIdx.x] = sh[255];
}
__global__ __launch_bounds__(256) void k_scan2(){
  __shared__ int sh[256];
  int t = threadIdx.x;
  int val = (t < SCAN_B) ? g_partial[t] : 0;
  sh[t] = val; __syncthreads();
#pragma unroll
  for (int off = 1; off < 256; off <<= 1){
    int v = (t >= off) ? sh[t - off] : 0;
    __syncthreads(); sh[t] += v; __syncthreads();
  }
  if (t < SCAN_B) g_partial[t] = sh[t] - val;
  if (t == 255) g_rowptr[NN] = sh[255];
}
__global__ __launch_bounds__(256) void k_scan3(){
  int i = blockIdx.x * 256 + threadIdx.x;
  if (i < NN) g_rowptr[i] += g_partial[blockIdx.x];
}
__global__ void k_fill(const int* __restrict__ src, const int* __restrict__ tgt){
  int e = blockIdx.x * 256 + threadIdx.x;
  if (e >= NE) return;
  int t = tgt[e];
  int pos = g_rowptr[t] + atomicAdd(&g_cursor[t], 1);
  g_colidx[pos] = src[e];
}
__global__ __launch_bounds__(256, 4) void k_gemm1_ln(const void* __restrict__ Aext,
    const void* __restrict__ bias, const void* __restrict__ gamma,
    const void* __restrict__ beta){
  __shared__ float red[28 * 256];
  const int tid = threadIdx.x;
  const int w = tid >> 6, lane = tid & 63;
  const int m = lane & 15, q = lane >> 4;
  const int row0 = blockIdx.x * 16;
  const int isf32 = g_isf32;
  f32x4 acc[7] = {};
  body_gemm1_compute(Aext, row0, m, q, w * 128, isf32, acc);
#pragma unroll
  for (int t = 0; t < 7; t++)
#pragma unroll
    for (int r = 0; r < 4; r++)
      red[(t * 4 + r) * 256 + tid] = acc[t][r];
  __syncthreads();
  if (w != 0) return;
  body_gemm1_epi(red, row0, lane, m, q, isf32, bias, gamma, beta);
}
__global__ __launch_bounds__(256) void k_gemm2_ln(const void* __restrict__ bias,
    const void* __restrict__ gamma, const void* __restrict__ beta){
  const int wave = threadIdx.x >> 6, lane = threadIdx.x & 63;
  const int row0 = (blockIdx.x * 4 + wave) * 16;
  if (row0 >= NN) return;
  body_gemm2_ln(row0, lane & 15, lane >> 4, g_isf32, bias, gamma, beta);
}
__global__ __launch_bounds__(256) void k_rgcn(const void* __restrict__ bias){
  const int wave = threadIdx.x >> 6, lane = threadIdx.x & 63;
  const int row0 = (blockIdx.x * 4 + wave) * 16;
  if (row0 >= NN) return;
  body_rgcn(row0, lane & 15, lane >> 4, g_isf32, bias);
}
__global__ __launch_bounds__(256) void k_conv1(const void* __restrict__ bias){
  const int wave = threadIdx.x >> 6, lane = threadIdx.x & 63;
  const int row0 = (blockIdx.x * 4 + wave) * 16;
  if (row0 >= NN) return;
  body_conv1(row0, lane & 15, lane >> 4, g_isf32, bias);
}
__global__ __launch_bounds__(256) void k_gemm_c2(){
  const int wave = threadIdx.x >> 6, lane = threadIdx.x & 63;
  const int row0 = (blockIdx.x * 4 + wave) * 16;
  if (row0 >= NN) return;
  body_c2(row0, lane & 15, lane >> 4);
}
template<int MODE>
__global__ __launch_bounds__(256) void k_agg(){
  int node = blockIdx.x * 16 + (threadIdx.x >> 4);
  if (node >= NN) return;
  body_agg<MODE>(node, (threadIdx.x & 15) * 8);
}
__global__ __launch_bounds__(256) void k_agg_lsm(const void* __restrict__ bias,
                                                 void* __restrict__ outv){
  int node = blockIdx.x * 32 + (threadIdx.x >> 3);
  if (node >= NN) return;
  body_agglsm(node, (threadIdx.x & 7) * 8, g_isf32, bias, outv);
}

extern "C" void kernel_launch(void* const* d_in, const int* in_sizes, int n_in,
                              void* d_out, int out_size, void* d_ws, size_t ws_size,
                              hipStream_t stream){
  (void)in_sizes; (void)n_in; (void)out_size; (void)d_ws; (void)ws_size;
  const void* data_x = d_in[0];
  const int* ei = (const int*)d_in[1];
  const int* src = ei;
  const int* tgt = ei + NE;
  const void *W1 = d_in[3], *b1 = d_in[4], *gm1 = d_in[5], *be1 = d_in[6];
  const void *W2 = d_in[7], *b2 = d_in[8], *gm2 = d_in[9], *be2 = d_in[10];
  const void *Wrel = d_in[11], *Wself = d_in[12], *rb = d_in[13];
  const void *c1W = d_in[14], *c1b = d_in[15];
  const void *c2W = d_in[16], *c2b = d_in[17];

  k_detect_zero<<<1 + (NN + 255) / 256, 256, 0, stream>>>((const unsigned short*)data_x);
  k_transpose_all<<<(122880 + 255) / 256, 256, 0, stream>>>(W1, W2, Wself, Wrel, c1W, c2W);

  MegaArgs ma{data_x, src, tgt, b1, gm1, be1, b2, gm2, be2, rb, c1b, c2b, d_out};
  void* kargs[] = {&ma};
  hipError_t err = hipLaunchCooperativeKernel((void*)k_mega, dim3(MEGA_B), dim3(256),
                                              kargs, 0, stream);
  if (err != hipSuccess){
    // fallback: R10 13-kernel path (deterministic branch — same every call)
    const int G64 = (NN + 63) / 64;
    const int GA  = (NN + 15) / 16;
    k_deg<<<(NE + 255) / 256, 256, 0, stream>>>(tgt);
    k_scan1<<<SCAN_B, 256, 0, stream>>>();
    k_scan2<<<1, 256, 0, stream>>>();
    k_scan3<<<SCAN_B, 256, 0, stream>>>();
    k_fill<<<(NE + 255) / 256, 256, 0, stream>>>(src, tgt);
    k_gemm1_ln<<<3125, 256, 0, stream>>>(data_x, b1, gm1, be1);
    k_gemm2_ln<<<G64, 256, 0, stream>>>(b2, gm2, be2);
    k_agg<0><<<GA, 256, 0, stream>>>();
    k_rgcn<<<G64, 256, 0, stream>>>(rb);
    k_agg<1><<<GA, 256, 0, stream>>>();
    k_conv1<<<G64, 256, 0, stream>>>(c1b);
    k_gemm_c2<<<G64, 256, 0, stream>>>();
    k_agg_lsm<<<(NN + 31) / 32, 256, 0, stream>>>(c2b, d_out);
  }
}

// Round 12
// 484.738 us; speedup vs baseline: 3.8782x; 3.8782x over previous
//
#include <hip/hip_runtime.h>
#include <hip/hip_bf16.h>

typedef __attribute__((ext_vector_type(8))) short short8;
typedef __attribute__((ext_vector_type(8))) unsigned short ushort8;
typedef __attribute__((ext_vector_type(4))) float f32x4;

static constexpr int NN = 50000;   // nodes
static constexpr int NE = 800000;  // edges
static constexpr int SCAN_B = 196; // ceil(NN/256)

#define MFMA16x16x32 __builtin_amdgcn_mfma_f32_16x16x32_bf16

__device__ __forceinline__ float b2f(unsigned short u){
  unsigned v = ((unsigned)u) << 16;
  return __builtin_bit_cast(float, v);
}
__device__ __forceinline__ unsigned short f2b(float f){
  unsigned x = __builtin_bit_cast(unsigned, f);
  unsigned r = (x + 0x7fffu + ((x >> 16) & 1u)) >> 16;  // RNE
  return (unsigned short)r;
}

// ---------------- static device scratch
__device__ __align__(256) int   g_isf32;
__device__ __align__(256) unsigned short g_W1t  [112 * 512];
__device__ __align__(256) unsigned short g_W2t  [112 * 128];
__device__ __align__(256) unsigned short g_WselfT[112 * 128];
__device__ __align__(256) unsigned short g_WrelT [112 * 128];
__device__ __align__(256) unsigned short g_c1Wt [112 * 128];
__device__ __align__(256) unsigned short g_c2Wt [64 * 128];
__device__ __align__(256) unsigned short g_bufA[(size_t)NN * 128];  // holds [N,64] c2 out
__device__ __align__(256) unsigned short g_bufB[(size_t)NN * 128];  // x2
__device__ __align__(256) unsigned short g_bufC[(size_t)NN * 128];  // x3
__device__ __align__(256) int   g_deg[NN];
__device__ __align__(256) int   g_rowptr[NN + 1];
__device__ __align__(256) int   g_cursor[NN];
__device__ __align__(256) int   g_colidx[NE];
__device__ __align__(256) float g_dinv[NN];
__device__ __align__(256) int   g_partial[256];

__device__ __forceinline__ float ld_in(const void* p, int idx, int isf32){
  if (isf32) return ((const float*)p)[idx];
  return b2f(((const unsigned short*)p)[idx]);
}

// ---------------- prep kernels ----------------
__global__ void k_detect_zero(const unsigned short* __restrict__ x){
  if (blockIdx.x == 0){
    __shared__ int sh[256];
    int tid = threadIdx.x;
    int cnt = 0;
    for (int j = 0; j < 16; j++){
      unsigned short h = x[(size_t)(tid * 16 + j) * 2];
      int e = (h >> 7) & 0xFF;
      if (e >= 90 && e <= 160) cnt++;
    }
    sh[tid] = cnt;
    __syncthreads();
    for (int off = 128; off > 0; off >>= 1){
      if (tid < off) sh[tid] += sh[tid + off];
      __syncthreads();
    }
    if (tid == 0) g_isf32 = (sh[0] < 2458) ? 1 : 0;
  } else {
    int i = (blockIdx.x - 1) * 256 + threadIdx.x;
    if (i < NN){ g_deg[i] = 0; g_cursor[i] = 0; }
  }
}

__device__ __forceinline__ void xp_one(const void* W, unsigned short* Wt, int idx,
                                       int K, int Nc, int Kpad, int isf32){
  int n = idx / Kpad;
  int k = idx - n * Kpad;
  float v = 0.f;
  if (n < Nc && k < K) v = ld_in(W, k * Nc + n, isf32);
  Wt[idx] = f2b(v);
}
__global__ void k_transpose_all(const void* W1, const void* W2, const void* Wself,
                                const void* Wrel, const void* c1W, const void* c2W){
  int idx = blockIdx.x * 256 + threadIdx.x;
  const int isf32 = g_isf32;
  if (idx < 57344){ xp_one(W1, g_W1t, idx, 500, 100, 512, isf32); return; }
  idx -= 57344;
  if (idx < 14336){ xp_one(W2,    g_W2t,    idx, 100, 100, 128, isf32); return; }
  idx -= 14336;
  if (idx < 14336){ xp_one(Wself, g_WselfT, idx, 100, 100, 128, isf32); return; }
  idx -= 14336;
  if (idx < 14336){ xp_one(Wrel,  g_WrelT,  idx, 100, 100, 128, isf32); return; }
  idx -= 14336;
  if (idx < 14336){ xp_one(c1W,   g_c1Wt,   idx, 100, 100, 128, isf32); return; }
  idx -= 14336;
  if (idx < 8192){  xp_one(c2W,   g_c2Wt,   idx, 100, 64,  128, isf32); }
}

__global__ void k_deg(const int* __restrict__ tgt){
  int e = blockIdx.x * 256 + threadIdx.x;
  if (e < NE) atomicAdd(&g_deg[tgt[e]], 1);
}
__global__ __launch_bounds__(256) void k_scan1(){
  __shared__ int sh[256];
  int t = threadIdx.x;
  int i = blockIdx.x * 256 + t;
  int val = (i < NN) ? g_deg[i] : 0;
  sh[t] = val; __syncthreads();
#pragma unroll
  for (int off = 1; off < 256; off <<= 1){
    int v = (t >= off) ? sh[t - off] : 0;
    __syncthreads(); sh[t] += v; __syncthreads();
  }
  if (i < NN){ g_rowptr[i] = sh[t] - val; g_dinv[i] = rsqrtf((float)(val + 1)); }
  if (t == 255) g_partial[blockIdx.x] = sh[255];
}
__global__ __launch_bounds__(256) void k_scan2(){
  __shared__ int sh[256];
  int t = threadIdx.x;
  int val = (t < SCAN_B) ? g_partial[t] : 0;
  sh[t] = val; __syncthreads();
#pragma unroll
  for (int off = 1; off < 256; off <<= 1){
    int v = (t >= off) ? sh[t - off] : 0;
    __syncthreads(); sh[t] += v; __syncthreads();
  }
  if (t < SCAN_B) g_partial[t] = sh[t] - val;
  if (t == 255) g_rowptr[NN] = sh[255];
}
__global__ __launch_bounds__(256) void k_scan3(){
  int i = blockIdx.x * 256 + threadIdx.x;
  if (i < NN) g_rowptr[i] += g_partial[blockIdx.x];
}
__global__ void k_fill(const int* __restrict__ src, const int* __restrict__ tgt){
  int e = blockIdx.x * 256 + threadIdx.x;
  if (e >= NE) return;
  int t = tgt[e];
  int pos = g_rowptr[t] + atomicAdd(&g_cursor[t], 1);
  g_colidx[pos] = src[e];
}

// ---------------- shared device helpers ----------------

// GEMM1 compute (K-split): wave w handles K in [128w,128w+128) of 16 rows.
__device__ __forceinline__ void body_gemm1_compute(const void* Aext, int row0,
    int m, int q, int kbase, int isf32, f32x4* acc){
  if (isf32){
    const float* base = (const float*)Aext + (size_t)(row0 + m) * 500;
    f32x4 L[8];
#pragma unroll
    for (int c = 0; c < 4; c++){
      int col = kbase + c * 32 + q * 8;
      L[2 * c]     = *reinterpret_cast<const f32x4*>(base + min(col, 496));
      L[2 * c + 1] = *reinterpret_cast<const f32x4*>(base + min(col + 4, 496));
    }
#pragma unroll
    for (int c = 0; c < 4; c++){
      f32x4 lo = L[2 * c], hi = L[2 * c + 1];
      short8 a = {(short)f2b(lo[0]), (short)f2b(lo[1]), (short)f2b(lo[2]), (short)f2b(lo[3]),
                  (short)f2b(hi[0]), (short)f2b(hi[1]), (short)f2b(hi[2]), (short)f2b(hi[3])};
      const int k0 = kbase + c * 32 + q * 8;
#pragma unroll
      for (int t = 0; t < 7; t++){
        short8 b = *reinterpret_cast<const short8*>(g_W1t + (size_t)(t * 16 + m) * 512 + k0);
        acc[t] = MFMA16x16x32(a, b, acc[t], 0, 0, 0);
      }
    }
  } else {
    const unsigned short* base = (const unsigned short*)Aext + (size_t)(row0 + m) * 500;
    ushort4 U[8];
#pragma unroll
    for (int c = 0; c < 4; c++){
      int col = kbase + c * 32 + q * 8;
      U[2 * c]     = *reinterpret_cast<const ushort4*>(base + min(col, 496));
      U[2 * c + 1] = *reinterpret_cast<const ushort4*>(base + min(col + 4, 496));
    }
#pragma unroll
    for (int c = 0; c < 4; c++){
      ushort4 lo = U[2 * c], hi = U[2 * c + 1];
      short8 a = {(short)lo.x, (short)lo.y, (short)lo.z, (short)lo.w,
                  (short)hi.x, (short)hi.y, (short)hi.z, (short)hi.w};
      const int k0 = kbase + c * 32 + q * 8;
#pragma unroll
      for (int t = 0; t < 7; t++){
        short8 b = *reinterpret_cast<const short8*>(g_W1t + (size_t)(t * 16 + m) * 512 + k0);
        acc[t] = MFMA16x16x32(a, b, acc[t], 0, 0, 0);
      }
    }
  }
}

// build bf16 A-fragment from f32 LDS tile (stride 132 f32)
__device__ __forceinline__ short8 frag_from_lds(const float* xT, int m, int k0){
  const float* ax = xT + m * 132 + k0;
  short8 a = {(short)f2b(ax[0]), (short)f2b(ax[1]), (short)f2b(ax[2]), (short)f2b(ax[3]),
              (short)f2b(ax[4]), (short)f2b(ax[5]), (short)f2b(ax[6]), (short)f2b(ax[7])};
  return a;
}

// reduce red (28 vals/lane) + bias + LN + ReLU -> LDS xT f32 tile, pads zeroed
__device__ __forceinline__ void epi_ln_to_lds(const float* red, float* xT,
    int lane, int m, int q, int isf32,
    const void* bias, const void* gamma, const void* beta){
  float bf_[7], gf_[7], ef_[7];
#pragma unroll
  for (int t = 0; t < 7; t++){
    int col = t * 16 + m;
    bool ok = col < 100;
    bf_[t] = ok ? ld_in(bias, col, isf32)  : 0.f;
    gf_[t] = ok ? ld_in(gamma, col, isf32) : 0.f;
    ef_[t] = ok ? ld_in(beta, col, isf32)  : 0.f;
  }
#pragma unroll
  for (int r = 0; r < 4; r++){
    float vals[7], s1 = 0.f, s2 = 0.f;
#pragma unroll
    for (int t = 0; t < 7; t++){
      const float* rv = &red[(t * 4 + r) * 256];
      float v = rv[lane] + rv[64 + lane] + rv[128 + lane] + rv[192 + lane];
      int col = t * 16 + m;
      v = (col < 100) ? (v + bf_[t]) : 0.f;
      vals[t] = v; s1 += v; s2 += v * v;
    }
#pragma unroll
    for (int msk = 1; msk < 16; msk <<= 1){
      s1 += __shfl_xor(s1, msk, 64);
      s2 += __shfl_xor(s2, msk, 64);
    }
    float mu = s1 * 0.01f;
    float var = fmaxf(s2 * 0.01f - mu * mu, 0.f);
    float rstd = rsqrtf(var + 1e-5f);
    float* xrow = xT + (q * 4 + r) * 132;
#pragma unroll
    for (int t = 0; t < 7; t++){
      int col = t * 16 + m;
      float y = fmaxf((vals[t] - mu) * rstd * gf_[t] + ef_[t], 0.f);
      xrow[col] = (col < 100) ? y : 0.f;
    }
    xrow[112 + m] = 0.f;
  }
}

// reduce red + bias + LN + ReLU -> global bf16 rows (stride 128), pads zeroed
__device__ __forceinline__ void epi_ln_to_global(const float* red, unsigned short* outb,
    int row0, int lane, int m, int q, int isf32,
    const void* bias, const void* gamma, const void* beta){
  float bf_[7], gf_[7], ef_[7];
#pragma unroll
  for (int t = 0; t < 7; t++){
    int col = t * 16 + m;
    bool ok = col < 100;
    bf_[t] = ok ? ld_in(bias, col, isf32)  : 0.f;
    gf_[t] = ok ? ld_in(gamma, col, isf32) : 0.f;
    ef_[t] = ok ? ld_in(beta, col, isf32)  : 0.f;
  }
#pragma unroll
  for (int r = 0; r < 4; r++){
    float vals[7], s1 = 0.f, s2 = 0.f;
#pragma unroll
    for (int t = 0; t < 7; t++){
      const float* rv = &red[(t * 4 + r) * 256];
      float v = rv[lane] + rv[64 + lane] + rv[128 + lane] + rv[192 + lane];
      int col = t * 16 + m;
      v = (col < 100) ? (v + bf_[t]) : 0.f;
      vals[t] = v; s1 += v; s2 += v * v;
    }
#pragma unroll
    for (int msk = 1; msk < 16; msk <<= 1){
      s1 += __shfl_xor(s1, msk, 64);
      s2 += __shfl_xor(s2, msk, 64);
    }
    float mu = s1 * 0.01f;
    float var = fmaxf(s2 * 0.01f - mu * mu, 0.f);
    float rstd = rsqrtf(var + 1e-5f);
    unsigned short* orow = outb + (size_t)(row0 + q * 4 + r) * 128;
#pragma unroll
    for (int t = 0; t < 7; t++){
      int col = t * 16 + m;
      float y = fmaxf((vals[t] - mu) * rstd * gf_[t] + ef_[t], 0.f);
      orow[col] = f2b((col < 100) ? y : 0.f);
    }
    orow[112 + m] = 0;
  }
}

// reduce red + bias + ReLU -> global bf16 rows (stride 128), pads zeroed
__device__ __forceinline__ void epi_biasrelu_to_global(const float* red,
    unsigned short* outb, int row0, int lane, int m, int q, int isf32,
    const void* bias){
  float bf_[7];
#pragma unroll
  for (int t = 0; t < 7; t++){
    int col = t * 16 + m;
    bf_[t] = (col < 100) ? ld_in(bias, col, isf32) : 0.f;
  }
#pragma unroll
  for (int r = 0; r < 4; r++){
    unsigned short* orow = outb + (size_t)(row0 + q * 4 + r) * 128;
#pragma unroll
    for (int t = 0; t < 7; t++){
      const float* rv = &red[(t * 4 + r) * 256];
      float v = rv[lane] + rv[64 + lane] + rv[128 + lane] + rv[192 + lane];
      int col = t * 16 + m;
      float y = fmaxf(v + bf_[t], 0.f);
      orow[col] = f2b((col < 100) ? y : 0.f);
    }
    orow[112 + m] = 0;
  }
}

// reduce red + bias + ReLU -> LDS xT f32 tile, pads zeroed
__device__ __forceinline__ void epi_biasrelu_to_lds(const float* red, float* xT,
    int lane, int m, int q, int isf32, const void* bias){
  float bf_[7];
#pragma unroll
  for (int t = 0; t < 7; t++){
    int col = t * 16 + m;
    bf_[t] = (col < 100) ? ld_in(bias, col, isf32) : 0.f;
  }
#pragma unroll
  for (int r = 0; r < 4; r++){
    float* xrow = xT + (q * 4 + r) * 132;
#pragma unroll
    for (int t = 0; t < 7; t++){
      const float* rv = &red[(t * 4 + r) * 256];
      float v = rv[lane] + rv[64 + lane] + rv[128 + lane] + rv[192 + lane];
      int col = t * 16 + m;
      float y = fmaxf(v + bf_[t], 0.f);
      xrow[col] = (col < 100) ? y : 0.f;
    }
    xrow[112 + m] = 0.f;
  }
}

// gather-aggregate into LDS f32 tile. MODE 0: sum from bufB; MODE 1: norm from bufC.
template<int MODE>
__device__ __forceinline__ void agg_to_lds(int node, int nl, int c8, float* aggT){
  const unsigned short* x = (MODE == 1) ? g_bufC : g_bufB;
  float wt = (MODE != 0) ? g_dinv[node] : 1.f;
  float a[4][8];
#pragma unroll
  for (int j = 0; j < 4; j++)
#pragma unroll
    for (int k = 0; k < 8; k++) a[j][k] = 0.f;
  int p0 = g_rowptr[node], p1 = g_rowptr[node + 1];
  for (int p = p0; p < p1; p += 4){
    int sj[4]; float wj[4];
#pragma unroll
    for (int j = 0; j < 4; j++){
      bool ok = (p + j) < p1;
      sj[j] = ok ? g_colidx[p + j] : node;
      wj[j] = ok ? ((MODE != 0) ? g_dinv[sj[j]] * wt : 1.f) : 0.f;
    }
    ushort8 r[4];
#pragma unroll
    for (int j = 0; j < 4; j++)
      r[j] = *reinterpret_cast<const ushort8*>(&x[(size_t)sj[j] * 128 + c8]);
#pragma unroll
    for (int j = 0; j < 4; j++)
#pragma unroll
      for (int k = 0; k < 8; k++) a[j][k] += wj[j] * b2f((unsigned short)r[j][k]);
  }
  if (MODE != 0){
    float ws = wt * wt;
    ushort8 sv = *reinterpret_cast<const ushort8*>(&x[(size_t)node * 128 + c8]);
#pragma unroll
    for (int k = 0; k < 8; k++) a[0][k] += ws * b2f((unsigned short)sv[k]);
  }
  float* arow = aggT + nl * 132;
#pragma unroll
  for (int k = 0; k < 8; k++)
    arow[c8 + k] = a[0][k] + a[1][k] + a[2][k] + a[3][k];
}

// ---------------- fused kernels ----------------

// GEMM1(K-split)+LN -> x1 in LDS -> GEMM2(K-split)+LN -> bufB. 3125 blocks.
__global__ __launch_bounds__(256, 4) void k_gemm12(const void* __restrict__ Aext,
    const void* b1, const void* gm1, const void* be1,
    const void* b2, const void* gm2, const void* be2){
  __shared__ float red[28 * 256];
  __shared__ float xT[16 * 132];
  const int tid = threadIdx.x;
  const int w = tid >> 6, lane = tid & 63;
  const int m = lane & 15, q = lane >> 4;
  const int row0 = blockIdx.x * 16;
  const int isf32 = g_isf32;

  f32x4 acc[7] = {};
  body_gemm1_compute(Aext, row0, m, q, w * 128, isf32, acc);
#pragma unroll
  for (int t = 0; t < 7; t++)
#pragma unroll
    for (int r = 0; r < 4; r++)
      red[(t * 4 + r) * 256 + tid] = acc[t][r];
  __syncthreads();
  if (w == 0) epi_ln_to_lds(red, xT, lane, m, q, isf32, b1, gm1, be1);
  __syncthreads();

  // GEMM2: wave w owns k-chunk [32w, 32w+32)
  f32x4 acc2[7] = {};
  const int k0 = w * 32 + q * 8;
  {
    short8 a = frag_from_lds(xT, m, k0);
#pragma unroll
    for (int t = 0; t < 7; t++){
      short8 b = *reinterpret_cast<const short8*>(g_W2t + (size_t)(t * 16 + m) * 128 + k0);
      acc2[t] = MFMA16x16x32(a, b, acc2[t], 0, 0, 0);
    }
  }
#pragma unroll
  for (int t = 0; t < 7; t++)
#pragma unroll
    for (int r = 0; r < 4; r++)
      red[(t * 4 + r) * 256 + tid] = acc2[t][r];
  __syncthreads();
  if (w == 0) epi_ln_to_global(red, g_bufB, row0, lane, m, q, isf32, b2, gm2, be2);
}

// RGCN: agg(bufB)->LDS, dual GEMM (bufB global + agg LDS), bias+ReLU -> bufC.
__global__ __launch_bounds__(256, 4) void k_rgcn_f(const void* rb){
  __shared__ float red[28 * 256];
  __shared__ float aggT[16 * 132];
  const int tid = threadIdx.x;
  agg_to_lds<0>(blockIdx.x * 16 + (tid >> 4), tid >> 4, (tid & 15) * 8, aggT);
  __syncthreads();

  const int w = tid >> 6, lane = tid & 63;
  const int m = lane & 15, q = lane >> 4;
  const int row0 = blockIdx.x * 16;
  const int k0 = w * 32 + q * 8;
  f32x4 acc[7] = {};
  {
    short8 a1 = *reinterpret_cast<const short8*>(g_bufB + (size_t)(row0 + m) * 128 + k0);
#pragma unroll
    for (int t = 0; t < 7; t++){
      short8 b = *reinterpret_cast<const short8*>(g_WselfT + (size_t)(t * 16 + m) * 128 + k0);
      acc[t] = MFMA16x16x32(a1, b, acc[t], 0, 0, 0);
    }
    short8 a2 = frag_from_lds(aggT, m, k0);
#pragma unroll
    for (int t = 0; t < 7; t++){
      short8 b = *reinterpret_cast<const short8*>(g_WrelT + (size_t)(t * 16 + m) * 128 + k0);
      acc[t] = MFMA16x16x32(a2, b, acc[t], 0, 0, 0);
    }
  }
#pragma unroll
  for (int t = 0; t < 7; t++)
#pragma unroll
    for (int r = 0; r < 4; r++)
      red[(t * 4 + r) * 256 + tid] = acc[t][r];
  __syncthreads();
  if (w == 0) epi_biasrelu_to_global(red, g_bufC, row0, lane, m, q, g_isf32, rb);
}

// conv1+conv2: aggnorm(bufC)->LDS, conv1 GEMM+bias+ReLU->LDS, c2 GEMM -> bufA[N,64].
__global__ __launch_bounds__(256, 4) void k_conv_f(const void* c1b){
  __shared__ float red[28 * 256];
  __shared__ float aggT[16 * 132];
  const int tid = threadIdx.x;
  agg_to_lds<1>(blockIdx.x * 16 + (tid >> 4), tid >> 4, (tid & 15) * 8, aggT);
  __syncthreads();

  const int w = tid >> 6, lane = tid & 63;
  const int m = lane & 15, q = lane >> 4;
  const int row0 = blockIdx.x * 16;
  const int k0 = w * 32 + q * 8;
  f32x4 acc[7] = {};
  {
    short8 a = frag_from_lds(aggT, m, k0);
#pragma unroll
    for (int t = 0; t < 7; t++){
      short8 b = *reinterpret_cast<const short8*>(g_c1Wt + (size_t)(t * 16 + m) * 128 + k0);
      acc[t] = MFMA16x16x32(a, b, acc[t], 0, 0, 0);
    }
  }
#pragma unroll
  for (int t = 0; t < 7; t++)
#pragma unroll
    for (int r = 0; r < 4; r++)
      red[(t * 4 + r) * 256 + tid] = acc[t][r];
  __syncthreads();
  if (w == 0) epi_biasrelu_to_lds(red, aggT, lane, m, q, g_isf32, c1b);  // aggT reused as x4
  __syncthreads();

  // c2: [16,128] @ c2Wt -> [16,64]
  f32x4 acc2[4] = {};
  {
    short8 a = frag_from_lds(aggT, m, k0);
#pragma unroll
    for (int t = 0; t < 4; t++){
      short8 b = *reinterpret_cast<const short8*>(g_c2Wt + (size_t)(t * 16 + m) * 128 + k0);
      acc2[t] = MFMA16x16x32(a, b, acc2[t], 0, 0, 0);
    }
  }
#pragma unroll
  for (int t = 0; t < 4; t++)
#pragma unroll
    for (int r = 0; r < 4; r++)
      red[(t * 4 + r) * 256 + tid] = acc2[t][r];
  __syncthreads();
  if (w == 0){
#pragma unroll
    for (int r = 0; r < 4; r++){
      unsigned short* orow = g_bufA + (size_t)(row0 + q * 4 + r) * 64;
#pragma unroll
      for (int t = 0; t < 4; t++){
        const float* rv = &red[(t * 4 + r) * 256];
        float v = rv[lane] + rv[64 + lane] + rv[128 + lane] + rv[192 + lane];
        orow[t * 16 + m] = f2b(v);
      }
    }
  }
}

// conv2 aggregate (64-col rows in bufA) + bias + log_softmax -> out
__global__ __launch_bounds__(256) void k_agg_lsm(const void* __restrict__ bias,
                                                 void* __restrict__ outv){
  const int isf32 = g_isf32;
  int node = blockIdx.x * 32 + (threadIdx.x >> 3);
  if (node >= NN) return;
  const int c8 = (threadIdx.x & 7) * 8;
  float wt = g_dinv[node];
  float a[4][8];
#pragma unroll
  for (int j = 0; j < 4; j++)
#pragma unroll
    for (int k = 0; k < 8; k++) a[j][k] = 0.f;
  int p0 = g_rowptr[node], p1 = g_rowptr[node + 1];
  for (int p = p0; p < p1; p += 4){
    int sj[4]; float wj[4];
#pragma unroll
    for (int j = 0; j < 4; j++){
      bool ok = (p + j) < p1;
      sj[j] = ok ? g_colidx[p + j] : node;
      wj[j] = ok ? g_dinv[sj[j]] * wt : 0.f;
    }
    ushort8 r[4];
#pragma unroll
    for (int j = 0; j < 4; j++)
      r[j] = *reinterpret_cast<const ushort8*>(&g_bufA[(size_t)sj[j] * 64 + c8]);
#pragma unroll
    for (int j = 0; j < 4; j++)
#pragma unroll
      for (int k = 0; k < 8; k++) a[j][k] += wj[j] * b2f((unsigned short)r[j][k]);
  }
  float ws = wt * wt;
  ushort8 sv = *reinterpret_cast<const ushort8*>(&g_bufA[(size_t)node * 64 + c8]);
#pragma unroll
  for (int k = 0; k < 8; k++) a[0][k] += ws * b2f((unsigned short)sv[k]);

  float v[8], mx = -1e30f;
#pragma unroll
  for (int k = 0; k < 8; k++){
    v[k] = a[0][k] + a[1][k] + a[2][k] + a[3][k] + ld_in(bias, c8 + k, isf32);
    mx = fmaxf(mx, v[k]);
  }
#pragma unroll
  for (int msk = 1; msk < 8; msk <<= 1) mx = fmaxf(mx, __shfl_xor(mx, msk, 64));
  float se = 0.f;
#pragma unroll
  for (int k = 0; k < 8; k++) se += expf(v[k] - mx);
#pragma unroll
  for (int msk = 1; msk < 8; msk <<= 1) se += __shfl_xor(se, msk, 64);
  float lse = logf(se);
  size_t ro = (size_t)node * 64 + c8;
  if (isf32){
    float* o = (float*)outv + ro;
#pragma unroll
    for (int k = 0; k < 8; k++) o[k] = v[k] - mx - lse;
  } else {
    unsigned short* o = (unsigned short*)outv + ro;
#pragma unroll
    for (int k = 0; k < 8; k++) o[k] = f2b(v[k] - mx - lse);
  }
}

extern "C" void kernel_launch(void* const* d_in, const int* in_sizes, int n_in,
                              void* d_out, int out_size, void* d_ws, size_t ws_size,
                              hipStream_t stream){
  (void)in_sizes; (void)n_in; (void)out_size; (void)d_ws; (void)ws_size;
  const void* data_x = d_in[0];
  const int* ei = (const int*)d_in[1];
  const int* src = ei;
  const int* tgt = ei + NE;
  const void *W1 = d_in[3], *b1 = d_in[4], *gm1 = d_in[5], *be1 = d_in[6];
  const void *W2 = d_in[7], *b2 = d_in[8], *gm2 = d_in[9], *be2 = d_in[10];
  const void *Wrel = d_in[11], *Wself = d_in[12], *rb = d_in[13];
  const void *c1W = d_in[14], *c1b = d_in[15];
  const void *c2W = d_in[16], *c2b = d_in[17];

  k_detect_zero<<<1 + (NN + 255) / 256, 256, 0, stream>>>((const unsigned short*)data_x);
  k_transpose_all<<<(122880 + 255) / 256, 256, 0, stream>>>(W1, W2, Wself, Wrel, c1W, c2W);

  k_deg<<<(NE + 255) / 256, 256, 0, stream>>>(tgt);
  k_scan1<<<SCAN_B, 256, 0, stream>>>();
  k_scan2<<<1, 256, 0, stream>>>();
  k_scan3<<<SCAN_B, 256, 0, stream>>>();
  k_fill<<<(NE + 255) / 256, 256, 0, stream>>>(src, tgt);

  k_gemm12<<<3125, 256, 0, stream>>>(data_x, b1, gm1, be1, b2, gm2, be2); // -> bufB
  k_rgcn_f<<<3125, 256, 0, stream>>>(rb);                                 // bufB -> bufC
  k_conv_f<<<3125, 256, 0, stream>>>(c1b);                                // bufC -> bufA[N,64]
  k_agg_lsm<<<(NN + 31) / 32, 256, 0, stream>>>(c2b, d_out);              // bufA -> out
}